// Round 1
// baseline (367.850 us; speedup 1.0000x reference)
//
#include <hip/hip_runtime.h>
#include <stdint.h>

typedef __bf16 bf16;
typedef __bf16 bf16x4 __attribute__((ext_vector_type(4)));
typedef __bf16 bf16x8 __attribute__((ext_vector_type(8)));
typedef float  f32x4  __attribute__((ext_vector_type(4)));

#define DIM   768
#define HEADS 12
#define HD    64
#define SEQ   4096
#define NBH   96   // 8 * 12

// ---- async global->LDS, 16B per lane (CK-style addrspace trick) ----
__device__ __forceinline__ void gload16(const void* g, void* l) {
  typedef const __attribute__((address_space(1))) uint32_t* gp_t;
  typedef __attribute__((address_space(3))) uint32_t* lp_t;
  gp_t gp = reinterpret_cast<gp_t>(reinterpret_cast<uintptr_t>(g));
  lp_t lp = reinterpret_cast<lp_t>(reinterpret_cast<uintptr_t>(l));
  __builtin_amdgcn_global_load_lds(gp, lp, 16, 0, 0);
}

// ---- weight fp32 -> bf16 convert ----
__global__ __launch_bounds__(256) void wcvt_kernel(const float* __restrict__ src,
                                                   bf16* __restrict__ dst) {
  int i = (blockIdx.x * 256 + threadIdx.x) * 4;
  float4 v = *reinterpret_cast<const float4*>(src + i);
  bf16x4 o;
  o[0] = (bf16)v.x; o[1] = (bf16)v.y; o[2] = (bf16)v.z; o[3] = (bf16)v.w;
  *reinterpret_cast<bf16x4*>(dst + i) = o;
}

// ---- LayerNorm: one wave per row, fp32 stats, bf16 out ----
__global__ __launch_bounds__(256) void ln_kernel(const float* __restrict__ x,
    const float* __restrict__ gam, const float* __restrict__ bet,
    bf16* __restrict__ y) {
  const int tid = threadIdx.x, w = tid >> 6, l = tid & 63;
  const int row = blockIdx.x * 4 + w;
  const float* xr = x + (long)row * DIM;
  float4 v[3];
  float s = 0.f, ss = 0.f;
#pragma unroll
  for (int j = 0; j < 3; j++) {
    v[j] = *reinterpret_cast<const float4*>(xr + l * 4 + j * 256);
    s  += v[j].x + v[j].y + v[j].z + v[j].w;
    ss += v[j].x * v[j].x + v[j].y * v[j].y + v[j].z * v[j].z + v[j].w * v[j].w;
  }
#pragma unroll
  for (int m = 1; m < 64; m <<= 1) { s += __shfl_xor(s, m); ss += __shfl_xor(ss, m); }
  const float mu = s * (1.f / 768.f);
  const float rstd = rsqrtf(ss * (1.f / 768.f) - mu * mu + 1e-5f);
  bf16* yr = y + (long)row * DIM;
#pragma unroll
  for (int j = 0; j < 3; j++) {
    int c = l * 4 + j * 256;
    float4 g4 = *reinterpret_cast<const float4*>(gam + c);
    float4 b4 = *reinterpret_cast<const float4*>(bet + c);
    bf16x4 o;
    o[0] = (bf16)((v[j].x - mu) * rstd * g4.x + b4.x);
    o[1] = (bf16)((v[j].y - mu) * rstd * g4.y + b4.y);
    o[2] = (bf16)((v[j].z - mu) * rstd * g4.z + b4.z);
    o[3] = (bf16)((v[j].w - mu) * rstd * g4.w + b4.w);
    *reinterpret_cast<bf16x4*>(yr + c) = o;
  }
}

// ---- 128x128 bf16 MFMA GEMM, C = A[M,768] * Bw[N,768]^T ----
// MODE 0: qkv (elu+1 on q,k; scatter to per-head [bh][n][d] bufs)
// MODE 1: proj (+bias, fp32 out [t][768])
template <int MODE>
__global__ __launch_bounds__(256) void gemm_kernel(
    const bf16* __restrict__ A, const bf16* __restrict__ Bw,
    bf16* __restrict__ qb, bf16* __restrict__ kb, bf16* __restrict__ vb,
    float* __restrict__ outp, const float* __restrict__ bias) {
  __shared__ __align__(16) bf16 As[128 * 32];
  __shared__ __align__(16) bf16 Bs[128 * 32];
  __shared__ __align__(16) bf16 Cs[128 * 128];
  const int tid = threadIdx.x;
  const int w = tid >> 6, l = tid & 63;
  const int wr = w >> 1, wc = w & 1;
  const int l16 = l & 15, l4 = l >> 4;
  const int mt = blockIdx.y, nt = blockIdx.x;

  const int kcol = (tid & 3) * 8;
  const bf16* agp0 = A + (mt * 128 + (tid >> 2)) * DIM + kcol;
  const bf16* agp1 = agp0 + 64 * DIM;
  const bf16* bgp0 = Bw + (nt * 128 + (tid >> 2)) * DIM + kcol;
  const bf16* bgp1 = bgp0 + 64 * DIM;

  f32x4 acc[4][4];
#pragma unroll
  for (int m = 0; m < 4; m++)
#pragma unroll
    for (int n = 0; n < 4; n++) { f32x4 z4 = {0.f, 0.f, 0.f, 0.f}; acc[m][n] = z4; }

  for (int k0 = 0; k0 < DIM; k0 += 32) {
    __syncthreads();
    gload16(agp0 + k0, As + tid * 8);
    gload16(agp1 + k0, As + 2048 + tid * 8);
    gload16(bgp0 + k0, Bs + tid * 8);
    gload16(bgp1 + k0, Bs + 2048 + tid * 8);
    __syncthreads();
    bf16x8 af[4], bfr[4];
#pragma unroll
    for (int m = 0; m < 4; m++)
      af[m] = *reinterpret_cast<const bf16x8*>(As + (wr * 64 + m * 16 + l16) * 32 + l4 * 8);
#pragma unroll
    for (int n = 0; n < 4; n++)
      bfr[n] = *reinterpret_cast<const bf16x8*>(Bs + (wc * 64 + n * 16 + l16) * 32 + l4 * 8);
#pragma unroll
    for (int m = 0; m < 4; m++)
#pragma unroll
      for (int n = 0; n < 4; n++)
        acc[m][n] = __builtin_amdgcn_mfma_f32_16x16x32_bf16(af[m], bfr[n], acc[m][n], 0, 0, 0);
  }

  if (MODE == 0) {
    const int s = nt / 6;   // 0=q, 1=k, 2=v (uniform per block)
    const int j = nt % 6;   // head pair
    __syncthreads();
#pragma unroll
    for (int m = 0; m < 4; m++)
#pragma unroll
      for (int n = 0; n < 4; n++)
#pragma unroll
        for (int i = 0; i < 4; i++) {
          float val = acc[m][n][i];
          if (s < 2) val = val > 0.f ? val + 1.f : __expf(val);
          Cs[(wr * 64 + m * 16 + l4 * 4 + i) * 128 + wc * 64 + n * 16 + l16] = (bf16)val;
        }
    __syncthreads();
    bf16* dst0 = (s == 0) ? qb : (s == 1) ? kb : vb;
#pragma unroll
    for (int r = 0; r < 8; r++) {
      int idx = r * 2048 + tid * 8;
      int row = idx >> 7, col = idx & 127;
      int t = mt * 128 + row;
      int b = t >> 12, ntok = t & 4095;
      int h = j * 2 + (col >> 6), d = col & 63;
      *reinterpret_cast<bf16x8*>(dst0 + (((b * HEADS + h) * SEQ + ntok) * HD + d)) =
          *reinterpret_cast<const bf16x8*>(Cs + idx);
    }
  } else {
#pragma unroll
    for (int n = 0; n < 4; n++) {
      int col = nt * 128 + wc * 64 + n * 16 + l16;
      float bv = bias[col];
#pragma unroll
      for (int m = 0; m < 4; m++)
#pragma unroll
        for (int i = 0; i < 4; i++) {
          int t = mt * 128 + wr * 64 + m * 16 + l4 * 4 + i;
          outp[t * DIM + col] = acc[m][n][i] + bv;
        }
    }
  }
}

// ---- kv partials: per (head, split of 512 tokens): kv[64][64] += k^T v ; ksum ----
__global__ __launch_bounds__(256) void kv_kernel(
    const bf16* __restrict__ kb, const bf16* __restrict__ vb,
    float* __restrict__ kv_part, float* __restrict__ ks_part) {
  __shared__ __align__(16) union UU {
    struct { bf16 Ks[128 * 64]; bf16 Vs[128 * 64]; } s;
    float red[8192];
  } u;
  __shared__ float ksred[4][64];
  const int head = blockIdx.x, sp = blockIdx.y;
  const int tid = threadIdx.x, w = tid >> 6, l = tid & 63;
  const int d0 = (l >> 3) * 8, e0 = (l & 7) * 8;
  const bf16* K = kb + (long)(head * SEQ + sp * 512) * HD;
  const bf16* V = vb + (long)(head * SEQ + sp * 512) * HD;
  float acc[8][8];
#pragma unroll
  for (int i = 0; i < 8; i++)
#pragma unroll
    for (int jj = 0; jj < 8; jj++) acc[i][jj] = 0.f;
  float ks[8] = {0.f, 0.f, 0.f, 0.f, 0.f, 0.f, 0.f, 0.f};

  for (int t0 = 0; t0 < 512; t0 += 128) {
    __syncthreads();
#pragma unroll
    for (int r = 0; r < 4; r++) {
      gload16(K + t0 * 64 + r * 2048 + tid * 8, u.s.Ks + r * 2048 + tid * 8);
      gload16(V + t0 * 64 + r * 2048 + tid * 8, u.s.Vs + r * 2048 + tid * 8);
    }
    __syncthreads();
    for (int n = w * 32; n < w * 32 + 32; n++) {
      bf16x8 k8 = *reinterpret_cast<const bf16x8*>(u.s.Ks + n * 64 + d0);
      bf16x8 v8 = *reinterpret_cast<const bf16x8*>(u.s.Vs + n * 64 + e0);
      float kf[8], vf[8];
#pragma unroll
      for (int i = 0; i < 8; i++) { kf[i] = (float)k8[i]; vf[i] = (float)v8[i]; }
#pragma unroll
      for (int i = 0; i < 8; i++) {
        ks[i] += kf[i];
#pragma unroll
        for (int jj = 0; jj < 8; jj++) acc[i][jj] += kf[i] * vf[jj];
      }
    }
  }
  if ((l & 7) == 0) {
#pragma unroll
    for (int i = 0; i < 8; i++) ksred[w][d0 + i] = ks[i];
  }
  __syncthreads();
  if (w >= 2) {
    float* dst = u.red + (w - 2) * 4096;
#pragma unroll
    for (int i = 0; i < 8; i++) {
      f32x4 a = {acc[i][0], acc[i][1], acc[i][2], acc[i][3]};
      f32x4 b = {acc[i][4], acc[i][5], acc[i][6], acc[i][7]};
      *reinterpret_cast<f32x4*>(dst + (d0 + i) * 64 + e0) = a;
      *reinterpret_cast<f32x4*>(dst + (d0 + i) * 64 + e0 + 4) = b;
    }
  }
  __syncthreads();
  if (w < 2) {
    const float* src = u.red + w * 4096;
#pragma unroll
    for (int i = 0; i < 8; i++)
#pragma unroll
      for (int jj = 0; jj < 8; jj++) acc[i][jj] += src[(d0 + i) * 64 + e0 + jj];
  }
  __syncthreads();
  if (w == 1) {
    float* dst = u.red;
#pragma unroll
    for (int i = 0; i < 8; i++) {
      f32x4 a = {acc[i][0], acc[i][1], acc[i][2], acc[i][3]};
      f32x4 b = {acc[i][4], acc[i][5], acc[i][6], acc[i][7]};
      *reinterpret_cast<f32x4*>(dst + (d0 + i) * 64 + e0) = a;
      *reinterpret_cast<f32x4*>(dst + (d0 + i) * 64 + e0 + 4) = b;
    }
  }
  __syncthreads();
  if (w == 0) {
    const float* src = u.red;
#pragma unroll
    for (int i = 0; i < 8; i++)
#pragma unroll
      for (int jj = 0; jj < 8; jj++) acc[i][jj] += src[(d0 + i) * 64 + e0 + jj];
    float* dst = kv_part + (long)(head * 8 + sp) * 4096;
#pragma unroll
    for (int i = 0; i < 8; i++) {
      f32x4 a = {acc[i][0], acc[i][1], acc[i][2], acc[i][3]};
      f32x4 b = {acc[i][4], acc[i][5], acc[i][6], acc[i][7]};
      *reinterpret_cast<f32x4*>(dst + (d0 + i) * 64 + e0) = a;
      *reinterpret_cast<f32x4*>(dst + (d0 + i) * 64 + e0 + 4) = b;
    }
  }
  if (tid < 64)
    ks_part[(head * 8 + sp) * 64 + tid] =
        ksred[0][tid] + ksred[1][tid] + ksred[2][tid] + ksred[3][tid];
}

// ---- finalize: sum partials -> kvT bf16 [head][e][d], ksum fp32 [head][d] ----
__global__ __launch_bounds__(256) void kvfin_kernel(const float* __restrict__ kv_part,
    const float* __restrict__ ks_part, bf16* __restrict__ kvT, float* __restrict__ ksum) {
  const int head = blockIdx.x, tid = threadIdx.x;
  const long base = (long)head * 8 * 4096;
  const int d = tid >> 2, ecol = (tid & 3) * 16;
  float s[16];
#pragma unroll
  for (int q = 0; q < 16; q++) s[q] = 0.f;
  for (int sp = 0; sp < 8; sp++) {
    const float* p = kv_part + base + sp * 4096 + d * 64 + ecol;
#pragma unroll
    for (int q = 0; q < 16; q++) s[q] += p[q];
  }
#pragma unroll
  for (int q = 0; q < 16; q++) kvT[head * 4096 + (ecol + q) * 64 + d] = (bf16)s[q];
  if (tid < 64) {
    float t = 0.f;
    for (int sp = 0; sp < 8; sp++) t += ks_part[(head * 8 + sp) * 64 + tid];
    ksum[head * 64 + tid] = t;
  }
}

// ---- out_pre = (Q @ kv) * z, bf16 out in [t][768] layout ----
__global__ __launch_bounds__(256) void qout_kernel(const bf16* __restrict__ qb,
    const bf16* __restrict__ kvT, const float* __restrict__ ksum,
    bf16* __restrict__ outp) {
  __shared__ __align__(16) bf16 Qs[128 * 64];
  __shared__ __align__(16) bf16 Bs2[64 * 64];
  __shared__ float ksum_s[64];
  __shared__ float z_s[128];
  const int head = blockIdx.x, tt = blockIdx.y;
  const int b = head / HEADS, h = head % HEADS;
  const int tid = threadIdx.x, w = tid >> 6, l = tid & 63;
  const int l16 = l & 15, l4 = l >> 4;
  const bf16* Qg = qb + (long)(head * SEQ + tt * 128) * HD;
#pragma unroll
  for (int r = 0; r < 4; r++) gload16(Qg + r * 2048 + tid * 8, Qs + r * 2048 + tid * 8);
#pragma unroll
  for (int r = 0; r < 2; r++)
    gload16(kvT + head * 4096 + r * 2048 + tid * 8, Bs2 + r * 2048 + tid * 8);
  if (tid < 64) ksum_s[tid] = ksum[head * 64 + tid];
  __syncthreads();
  if (tid < 128) {  // denominator per token (reads global q, L2-hot)
    float dsum = 0.f;
#pragma unroll
    for (int i = 0; i < 8; i++) {
      bf16x8 q8 = *reinterpret_cast<const bf16x8*>(Qg + tid * 64 + i * 8);
#pragma unroll
      for (int jj = 0; jj < 8; jj++) dsum += (float)q8[jj] * ksum_s[i * 8 + jj];
    }
    z_s[tid] = 1.f / (dsum + 1e-6f);
  }
  f32x4 acc[2][4];
#pragma unroll
  for (int m = 0; m < 2; m++)
#pragma unroll
    for (int n = 0; n < 4; n++) { f32x4 z4 = {0.f, 0.f, 0.f, 0.f}; acc[m][n] = z4; }
#pragma unroll
  for (int kk = 0; kk < 2; kk++) {
    bf16x8 af[2], bfr[4];
#pragma unroll
    for (int m = 0; m < 2; m++)
      af[m] = *reinterpret_cast<const bf16x8*>(Qs + (w * 32 + m * 16 + l16) * 64 + kk * 32 + l4 * 8);
#pragma unroll
    for (int n = 0; n < 4; n++)
      bfr[n] = *reinterpret_cast<const bf16x8*>(Bs2 + (n * 16 + l16) * 64 + kk * 32 + l4 * 8);
#pragma unroll
    for (int m = 0; m < 2; m++)
#pragma unroll
      for (int n = 0; n < 4; n++)
        acc[m][n] = __builtin_amdgcn_mfma_f32_16x16x32_bf16(af[m], bfr[n], acc[m][n], 0, 0, 0);
  }
  __syncthreads();
#pragma unroll
  for (int m = 0; m < 2; m++)
#pragma unroll
    for (int n = 0; n < 4; n++)
#pragma unroll
      for (int i = 0; i < 4; i++) {
        int row = w * 32 + m * 16 + l4 * 4 + i;
        Qs[row * 64 + n * 16 + l16] = (bf16)(acc[m][n][i] * z_s[row]);
      }
  __syncthreads();
#pragma unroll
  for (int r = 0; r < 4; r++) {
    int idx = r * 2048 + tid * 8;
    int row = idx >> 6, col = idx & 63;
    *reinterpret_cast<bf16x8*>(outp + (long)(b * SEQ + tt * 128 + row) * DIM + h * HD + col) =
        *reinterpret_cast<const bf16x8*>(Qs + idx);
  }
}

extern "C" void kernel_launch(void* const* d_in, const int* in_sizes, int n_in,
                              void* d_out, int out_size, void* d_ws, size_t ws_size,
                              hipStream_t stream) {
  const float* x     = (const float*)d_in[0];
  const float* gam   = (const float*)d_in[1];
  const float* bet   = (const float*)d_in[2];
  const float* wqkv  = (const float*)d_in[3];
  const float* wproj = (const float*)d_in[4];
  const float* bproj = (const float*)d_in[5];
  float* out = (float*)d_out;
  char* ws = (char*)d_ws;

  bf16*  y       = (bf16*)(ws);                    // 50331648 B (reused as out_pre)
  bf16*  qb      = (bf16*)(ws + 50331648);         // 50331648 B
  bf16*  kb      = (bf16*)(ws + 100663296);        // 50331648 B
  bf16*  vb      = (bf16*)(ws + 150994944);        // 50331648 B
  bf16*  wqkv_b  = (bf16*)(ws + 201326592);        // 3538944 B
  bf16*  wproj_b = (bf16*)(ws + 204865536);        // 1179648 B
  float* kv_part = (float*)(ws + 206045184);       // 12582912 B
  float* ks_part = (float*)(ws + 218628096);       // 196608 B
  bf16*  kvT     = (bf16*)(ws + 218824704);        // 786432 B
  float* ksum    = (float*)(ws + 219611136);       // 24576 B

  wcvt_kernel<<<1728, 256, 0, stream>>>(wqkv, wqkv_b);
  wcvt_kernel<<<576, 256, 0, stream>>>(wproj, wproj_b);
  ln_kernel<<<8192, 256, 0, stream>>>(x, gam, bet, y);
  gemm_kernel<0><<<dim3(18, 256), 256, 0, stream>>>(y, wqkv_b, qb, kb, vb, nullptr, nullptr);
  kv_kernel<<<dim3(96, 8), 256, 0, stream>>>(kb, vb, kv_part, ks_part);
  kvfin_kernel<<<96, 256, 0, stream>>>(kv_part, ks_part, kvT, ksum);
  qout_kernel<<<dim3(96, 32), 256, 0, stream>>>(qb, kvT, ksum, y);
  gemm_kernel<1><<<dim3(6, 256), 256, 0, stream>>>(y, wproj_b, nullptr, nullptr, nullptr, out, bproj);
}

// Round 2
// 367.384 us; speedup vs baseline: 1.0013x; 1.0013x over previous
//
#include <hip/hip_runtime.h>
#include <stdint.h>

typedef __bf16 bf16;
typedef __bf16 bf16x4 __attribute__((ext_vector_type(4)));
typedef __bf16 bf16x8 __attribute__((ext_vector_type(8)));
typedef float  f32x4  __attribute__((ext_vector_type(4)));

#define DIM   768
#define HEADS 12
#define HD    64
#define SEQ   4096
#define NBH   96   // 8 * 12

// ---- async global->LDS, 16B per lane ----
__device__ __forceinline__ void gload16(const void* g, void* l) {
  typedef const __attribute__((address_space(1))) uint32_t* gp_t;
  typedef __attribute__((address_space(3))) uint32_t* lp_t;
  gp_t gp = reinterpret_cast<gp_t>(reinterpret_cast<uintptr_t>(g));
  lp_t lp = reinterpret_cast<lp_t>(reinterpret_cast<uintptr_t>(l));
  __builtin_amdgcn_global_load_lds(gp, lp, 16, 0, 0);
}

// ---- weight fp32 -> bf16 convert ----
__global__ __launch_bounds__(256) void wcvt_kernel(const float* __restrict__ src,
                                                   bf16* __restrict__ dst) {
  int i = (blockIdx.x * 256 + threadIdx.x) * 4;
  float4 v = *reinterpret_cast<const float4*>(src + i);
  bf16x4 o;
  o[0] = (bf16)v.x; o[1] = (bf16)v.y; o[2] = (bf16)v.z; o[3] = (bf16)v.w;
  *reinterpret_cast<bf16x4*>(dst + i) = o;
}

// ---- LayerNorm: one wave per row, fp32 stats, bf16 out ----
__global__ __launch_bounds__(256) void ln_kernel(const float* __restrict__ x,
    const float* __restrict__ gam, const float* __restrict__ bet,
    bf16* __restrict__ y) {
  const int tid = threadIdx.x, w = tid >> 6, l = tid & 63;
  const int row = blockIdx.x * 4 + w;
  const float* xr = x + (long)row * DIM;
  float4 v[3];
  float s = 0.f, ss = 0.f;
#pragma unroll
  for (int j = 0; j < 3; j++) {
    v[j] = *reinterpret_cast<const float4*>(xr + l * 4 + j * 256);
    s  += v[j].x + v[j].y + v[j].z + v[j].w;
    ss += v[j].x * v[j].x + v[j].y * v[j].y + v[j].z * v[j].z + v[j].w * v[j].w;
  }
#pragma unroll
  for (int m = 1; m < 64; m <<= 1) { s += __shfl_xor(s, m); ss += __shfl_xor(ss, m); }
  const float mu = s * (1.f / 768.f);
  const float rstd = rsqrtf(ss * (1.f / 768.f) - mu * mu + 1e-5f);
  bf16* yr = y + (long)row * DIM;
#pragma unroll
  for (int j = 0; j < 3; j++) {
    int c = l * 4 + j * 256;
    float4 g4 = *reinterpret_cast<const float4*>(gam + c);
    float4 b4 = *reinterpret_cast<const float4*>(bet + c);
    bf16x4 o;
    o[0] = (bf16)((v[j].x - mu) * rstd * g4.x + b4.x);
    o[1] = (bf16)((v[j].y - mu) * rstd * g4.y + b4.y);
    o[2] = (bf16)((v[j].z - mu) * rstd * g4.z + b4.z);
    o[3] = (bf16)((v[j].w - mu) * rstd * g4.w + b4.w);
    *reinterpret_cast<bf16x4*>(yr + c) = o;
  }
}

// ---- 128x128 bf16 MFMA GEMM, C = A[M,768] * Bw[N,768]^T ----
// MODE 0: qkv (elu+1 on q,k; scatter to per-head [bh][n][d] bufs), NT=18
// MODE 1: proj (+bias, fp32 out [t][768]), NT=6
template <int MODE>
__global__ __launch_bounds__(256) void gemm_kernel(
    const bf16* __restrict__ A, const bf16* __restrict__ Bw,
    bf16* __restrict__ qb, bf16* __restrict__ kb, bf16* __restrict__ vb,
    float* __restrict__ outp, const float* __restrict__ bias) {
  __shared__ __align__(16) bf16 As[128 * 32];
  __shared__ __align__(16) bf16 Bs[128 * 32];
  const int tid = threadIdx.x;
  const int w = tid >> 6, l = tid & 63;
  const int wr = w >> 1, wc = w & 1;
  const int l16 = l & 15, l4 = l >> 4;

  // T1: bijective XCD-aware swizzle (nwg % 8 == 0 for both modes).
  // Each XCD gets a contiguous wgid chunk sweeping nt fastest -> one A-panel
  // (196 KB) + the whole B (<=3.5 MB) stay resident in that XCD's 4MB L2.
  const int NT = (MODE == 0) ? 18 : 6;
  const int nwg = NT * 256;
  const int orig = blockIdx.x;
  const int wgid = (orig & 7) * (nwg >> 3) + (orig >> 3);
  const int mt = wgid / NT, nt = wgid % NT;

  const int kcol = (tid & 3) * 8;
  const bf16* agp0 = A + (mt * 128 + (tid >> 2)) * DIM + kcol;
  const bf16* agp1 = agp0 + 64 * DIM;
  const bf16* bgp0 = Bw + (nt * 128 + (tid >> 2)) * DIM + kcol;
  const bf16* bgp1 = bgp0 + 64 * DIM;

  f32x4 acc[4][4];
#pragma unroll
  for (int m = 0; m < 4; m++)
#pragma unroll
    for (int n = 0; n < 4; n++) { f32x4 z4 = {0.f, 0.f, 0.f, 0.f}; acc[m][n] = z4; }

  for (int k0 = 0; k0 < DIM; k0 += 32) {
    __syncthreads();
    gload16(agp0 + k0, As + tid * 8);
    gload16(agp1 + k0, As + 2048 + tid * 8);
    gload16(bgp0 + k0, Bs + tid * 8);
    gload16(bgp1 + k0, Bs + 2048 + tid * 8);
    __syncthreads();
    bf16x8 af[4], bfr[4];
#pragma unroll
    for (int m = 0; m < 4; m++)
      af[m] = *reinterpret_cast<const bf16x8*>(As + (wr * 64 + m * 16 + l16) * 32 + l4 * 8);
#pragma unroll
    for (int n = 0; n < 4; n++)
      bfr[n] = *reinterpret_cast<const bf16x8*>(Bs + (wc * 64 + n * 16 + l16) * 32 + l4 * 8);
#pragma unroll
    for (int m = 0; m < 4; m++)
#pragma unroll
      for (int n = 0; n < 4; n++)
        acc[m][n] = __builtin_amdgcn_mfma_f32_16x16x32_bf16(af[m], bfr[n], acc[m][n], 0, 0, 0);
  }

  if constexpr (MODE == 0) {
    // 2-pass epilogue through a 16KB Cs (keeps block LDS at 32KB -> 4 blk/CU).
    __shared__ __align__(16) bf16 Cs[128 * 64];
    const int s = nt / 6;   // 0=q, 1=k, 2=v (uniform per block)
    const int j = nt % 6;   // head pair
    bf16* dst0 = (s == 0) ? qb : (s == 1) ? kb : vb;
#pragma unroll
    for (int p = 0; p < 2; p++) {
      __syncthreads();
      if (wc == p) {
#pragma unroll
        for (int m = 0; m < 4; m++)
#pragma unroll
          for (int n = 0; n < 4; n++)
#pragma unroll
            for (int i = 0; i < 4; i++) {
              float val = acc[m][n][i];
              if (s < 2) val = val > 0.f ? val + 1.f : __expf(val);
              Cs[(wr * 64 + m * 16 + l4 * 4 + i) * 64 + n * 16 + l16] = (bf16)val;
            }
      }
      __syncthreads();
      const int h = j * 2 + p;
#pragma unroll
      for (int r = 0; r < 4; r++) {
        int idx = r * 2048 + tid * 8;
        int row = idx >> 6, col = idx & 63;
        int t = mt * 128 + row;
        int b = t >> 12, ntok = t & 4095;
        *reinterpret_cast<bf16x8*>(dst0 + (((b * HEADS + h) * SEQ + ntok) * HD + col)) =
            *reinterpret_cast<const bf16x8*>(Cs + idx);
      }
    }
  } else {
#pragma unroll
    for (int n = 0; n < 4; n++) {
      int col = nt * 128 + wc * 64 + n * 16 + l16;
      float bv = bias[col];
#pragma unroll
      for (int m = 0; m < 4; m++)
#pragma unroll
        for (int i = 0; i < 4; i++) {
          int t = mt * 128 + wr * 64 + m * 16 + l4 * 4 + i;
          outp[t * DIM + col] = acc[m][n][i] + bv;
        }
    }
  }
}

// ---- kv partials: per (head, split of 512 tokens): kv[64][64] += k^T v ; ksum ----
__global__ __launch_bounds__(256) void kv_kernel(
    const bf16* __restrict__ kb, const bf16* __restrict__ vb,
    float* __restrict__ kv_part, float* __restrict__ ks_part) {
  __shared__ __align__(16) union UU {
    struct { bf16 Ks[128 * 64]; bf16 Vs[128 * 64]; } s;
    float red[8192];
  } u;
  __shared__ float ksred[4][64];
  const int head = blockIdx.x, sp = blockIdx.y;
  const int tid = threadIdx.x, w = tid >> 6, l = tid & 63;
  const int d0 = (l >> 3) * 8, e0 = (l & 7) * 8;
  const bf16* K = kb + (long)(head * SEQ + sp * 512) * HD;
  const bf16* V = vb + (long)(head * SEQ + sp * 512) * HD;
  float acc[8][8];
#pragma unroll
  for (int i = 0; i < 8; i++)
#pragma unroll
    for (int jj = 0; jj < 8; jj++) acc[i][jj] = 0.f;
  float ks[8] = {0.f, 0.f, 0.f, 0.f, 0.f, 0.f, 0.f, 0.f};

  for (int t0 = 0; t0 < 512; t0 += 128) {
    __syncthreads();
#pragma unroll
    for (int r = 0; r < 4; r++) {
      gload16(K + t0 * 64 + r * 2048 + tid * 8, u.s.Ks + r * 2048 + tid * 8);
      gload16(V + t0 * 64 + r * 2048 + tid * 8, u.s.Vs + r * 2048 + tid * 8);
    }
    __syncthreads();
    for (int n = w * 32; n < w * 32 + 32; n++) {
      bf16x8 k8 = *reinterpret_cast<const bf16x8*>(u.s.Ks + n * 64 + d0);
      bf16x8 v8 = *reinterpret_cast<const bf16x8*>(u.s.Vs + n * 64 + e0);
      float kf[8], vf[8];
#pragma unroll
      for (int i = 0; i < 8; i++) { kf[i] = (float)k8[i]; vf[i] = (float)v8[i]; }
#pragma unroll
      for (int i = 0; i < 8; i++) {
        ks[i] += kf[i];
#pragma unroll
        for (int jj = 0; jj < 8; jj++) acc[i][jj] += kf[i] * vf[jj];
      }
    }
  }
  if ((l & 7) == 0) {
#pragma unroll
    for (int i = 0; i < 8; i++) ksred[w][d0 + i] = ks[i];
  }
  __syncthreads();
  if (w >= 2) {
    float* dst = u.red + (w - 2) * 4096;
#pragma unroll
    for (int i = 0; i < 8; i++) {
      f32x4 a = {acc[i][0], acc[i][1], acc[i][2], acc[i][3]};
      f32x4 b = {acc[i][4], acc[i][5], acc[i][6], acc[i][7]};
      *reinterpret_cast<f32x4*>(dst + (d0 + i) * 64 + e0) = a;
      *reinterpret_cast<f32x4*>(dst + (d0 + i) * 64 + e0 + 4) = b;
    }
  }
  __syncthreads();
  if (w < 2) {
    const float* src = u.red + w * 4096;
#pragma unroll
    for (int i = 0; i < 8; i++)
#pragma unroll
      for (int jj = 0; jj < 8; jj++) acc[i][jj] += src[(d0 + i) * 64 + e0 + jj];
  }
  __syncthreads();
  if (w == 1) {
    float* dst = u.red;
#pragma unroll
    for (int i = 0; i < 8; i++) {
      f32x4 a = {acc[i][0], acc[i][1], acc[i][2], acc[i][3]};
      f32x4 b = {acc[i][4], acc[i][5], acc[i][6], acc[i][7]};
      *reinterpret_cast<f32x4*>(dst + (d0 + i) * 64 + e0) = a;
      *reinterpret_cast<f32x4*>(dst + (d0 + i) * 64 + e0 + 4) = b;
    }
  }
  __syncthreads();
  if (w == 0) {
    const float* src = u.red;
#pragma unroll
    for (int i = 0; i < 8; i++)
#pragma unroll
      for (int jj = 0; jj < 8; jj++) acc[i][jj] += src[(d0 + i) * 64 + e0 + jj];
    float* dst = kv_part + (long)(head * 8 + sp) * 4096;
#pragma unroll
    for (int i = 0; i < 8; i++) {
      f32x4 a = {acc[i][0], acc[i][1], acc[i][2], acc[i][3]};
      f32x4 b = {acc[i][4], acc[i][5], acc[i][6], acc[i][7]};
      *reinterpret_cast<f32x4*>(dst + (d0 + i) * 64 + e0) = a;
      *reinterpret_cast<f32x4*>(dst + (d0 + i) * 64 + e0 + 4) = b;
    }
  }
  if (tid < 64)
    ks_part[(head * 8 + sp) * 64 + tid] =
        ksred[0][tid] + ksred[1][tid] + ksred[2][tid] + ksred[3][tid];
}

// ---- finalize: sum partials -> kvT bf16 [head][e][d], ksum fp32 [head][d] ----
__global__ __launch_bounds__(256) void kvfin_kernel(const float* __restrict__ kv_part,
    const float* __restrict__ ks_part, bf16* __restrict__ kvT, float* __restrict__ ksum) {
  const int head = blockIdx.x, tid = threadIdx.x;
  const long base = (long)head * 8 * 4096;
  const int d = tid >> 2, ecol = (tid & 3) * 16;
  float s[16];
#pragma unroll
  for (int q = 0; q < 16; q++) s[q] = 0.f;
  for (int sp = 0; sp < 8; sp++) {
    const float* p = kv_part + base + sp * 4096 + d * 64 + ecol;
#pragma unroll
    for (int q = 0; q < 16; q++) s[q] += p[q];
  }
#pragma unroll
  for (int q = 0; q < 16; q++) kvT[head * 4096 + (ecol + q) * 64 + d] = (bf16)s[q];
  if (tid < 64) {
    float t = 0.f;
    for (int sp = 0; sp < 8; sp++) t += ks_part[(head * 8 + sp) * 64 + tid];
    ksum[head * 64 + tid] = t;
  }
}

// ---- out_pre = (Q @ kv) * z, bf16 out in [t][768] layout ----
__global__ __launch_bounds__(256) void qout_kernel(const bf16* __restrict__ qb,
    const bf16* __restrict__ kvT, const float* __restrict__ ksum,
    bf16* __restrict__ outp) {
  __shared__ __align__(16) bf16 Qs[128 * 64];
  __shared__ __align__(16) bf16 Bs2[64 * 64];
  __shared__ float ksum_s[64];
  __shared__ float z_s[128];
  const int head = blockIdx.x, tt = blockIdx.y;
  const int b = head / HEADS, h = head % HEADS;
  const int tid = threadIdx.x, w = tid >> 6, l = tid & 63;
  const int l16 = l & 15, l4 = l >> 4;
  const bf16* Qg = qb + (long)(head * SEQ + tt * 128) * HD;
#pragma unroll
  for (int r = 0; r < 4; r++) gload16(Qg + r * 2048 + tid * 8, Qs + r * 2048 + tid * 8);
#pragma unroll
  for (int r = 0; r < 2; r++)
    gload16(kvT + head * 4096 + r * 2048 + tid * 8, Bs2 + r * 2048 + tid * 8);
  if (tid < 64) ksum_s[tid] = ksum[head * 64 + tid];
  __syncthreads();
  if (tid < 128) {  // denominator per token (reads global q, L2-hot)
    float dsum = 0.f;
#pragma unroll
    for (int i = 0; i < 8; i++) {
      bf16x8 q8 = *reinterpret_cast<const bf16x8*>(Qg + tid * 64 + i * 8);
#pragma unroll
      for (int jj = 0; jj < 8; jj++) dsum += (float)q8[jj] * ksum_s[i * 8 + jj];
    }
    z_s[tid] = 1.f / (dsum + 1e-6f);
  }
  f32x4 acc[2][4];
#pragma unroll
  for (int m = 0; m < 2; m++)
#pragma unroll
    for (int n = 0; n < 4; n++) { f32x4 z4 = {0.f, 0.f, 0.f, 0.f}; acc[m][n] = z4; }
#pragma unroll
  for (int kk = 0; kk < 2; kk++) {
    bf16x8 af[2], bfr[4];
#pragma unroll
    for (int m = 0; m < 2; m++)
      af[m] = *reinterpret_cast<const bf16x8*>(Qs + (w * 32 + m * 16 + l16) * 64 + kk * 32 + l4 * 8);
#pragma unroll
    for (int n = 0; n < 4; n++)
      bfr[n] = *reinterpret_cast<const bf16x8*>(Bs2 + (n * 16 + l16) * 64 + kk * 32 + l4 * 8);
#pragma unroll
    for (int m = 0; m < 2; m++)
#pragma unroll
      for (int n = 0; n < 4; n++)
        acc[m][n] = __builtin_amdgcn_mfma_f32_16x16x32_bf16(af[m], bfr[n], acc[m][n], 0, 0, 0);
  }
  __syncthreads();
#pragma unroll
  for (int m = 0; m < 2; m++)
#pragma unroll
    for (int n = 0; n < 4; n++)
#pragma unroll
      for (int i = 0; i < 4; i++) {
        int row = w * 32 + m * 16 + l4 * 4 + i;
        Qs[row * 64 + n * 16 + l16] = (bf16)(acc[m][n][i] * z_s[row]);
      }
  __syncthreads();
#pragma unroll
  for (int r = 0; r < 4; r++) {
    int idx = r * 2048 + tid * 8;
    int row = idx >> 6, col = idx & 63;
    *reinterpret_cast<bf16x8*>(outp + (long)(b * SEQ + tt * 128 + row) * DIM + h * HD + col) =
        *reinterpret_cast<const bf16x8*>(Qs + idx);
  }
}

extern "C" void kernel_launch(void* const* d_in, const int* in_sizes, int n_in,
                              void* d_out, int out_size, void* d_ws, size_t ws_size,
                              hipStream_t stream) {
  const float* x     = (const float*)d_in[0];
  const float* gam   = (const float*)d_in[1];
  const float* bet   = (const float*)d_in[2];
  const float* wqkv  = (const float*)d_in[3];
  const float* wproj = (const float*)d_in[4];
  const float* bproj = (const float*)d_in[5];
  float* out = (float*)d_out;
  char* ws = (char*)d_ws;

  bf16*  y       = (bf16*)(ws);                    // 50331648 B (reused as out_pre)
  bf16*  qb      = (bf16*)(ws + 50331648);         // 50331648 B
  bf16*  kb      = (bf16*)(ws + 100663296);        // 50331648 B
  bf16*  vb      = (bf16*)(ws + 150994944);        // 50331648 B
  bf16*  wqkv_b  = (bf16*)(ws + 201326592);        // 3538944 B
  bf16*  wproj_b = (bf16*)(ws + 204865536);        // 1179648 B
  float* kv_part = (float*)(ws + 206045184);       // 12582912 B
  float* ks_part = (float*)(ws + 218628096);       // 196608 B
  bf16*  kvT     = (bf16*)(ws + 218824704);        // 786432 B
  float* ksum    = (float*)(ws + 219611136);       // 24576 B

  wcvt_kernel<<<1728, 256, 0, stream>>>(wqkv, wqkv_b);
  wcvt_kernel<<<576, 256, 0, stream>>>(wproj, wproj_b);
  ln_kernel<<<8192, 256, 0, stream>>>(x, gam, bet, y);
  gemm_kernel<0><<<dim3(18 * 256), 256, 0, stream>>>(y, wqkv_b, qb, kb, vb, nullptr, nullptr);
  kv_kernel<<<dim3(96, 8), 256, 0, stream>>>(kb, vb, kv_part, ks_part);
  kvfin_kernel<<<96, 256, 0, stream>>>(kv_part, ks_part, kvT, ksum);
  qout_kernel<<<dim3(96, 32), 256, 0, stream>>>(qb, kvT, ksum, y);
  gemm_kernel<1><<<dim3(6 * 256), 256, 0, stream>>>(y, wproj_b, nullptr, nullptr, nullptr, out, bproj);
}